// Round 1
// baseline (140.255 us; speedup 1.0000x reference)
//
#include <hip/hip_runtime.h>
#include <hip/hip_bf16.h>
#include <math.h>

#define FSE_HW     524288   // 512 * 1024
#define FSE_C      512
#define FSE_K      19
#define FSE_NS     8192     // sampled pixels
#define WAVES_PER_BLOCK 4

__global__ __launch_bounds__(256) void fse_zero_kernel(float4* __restrict__ out) {
    // 524288 floats = 131072 float4; grid = 512 blocks * 256 threads
    int i = blockIdx.x * 256 + threadIdx.x;
    out[i] = make_float4(0.f, 0.f, 0.f, 0.f);
}

__global__ __launch_bounds__(256) void fse_main_kernel(
        const float* __restrict__ feats,    // (C, HW) after dropping batch: c*HW + idx
        const float* __restrict__ outs,     // (K, HW)
        const float* __restrict__ protos,   // (K, C)
        const int*   __restrict__ sidx,     // (NS,)
        float* __restrict__ out)            // (HW,)
{
    __shared__ float sP[FSE_K * FSE_C];     // 38912 B

    const int tid = threadIdx.x;
    // stage prototypes into LDS (coalesced)
    for (int i = tid; i < FSE_K * FSE_C; i += 256) sP[i] = protos[i];

    const int wave = tid >> 6;
    const int lane = tid & 63;
    const int s    = blockIdx.x * WAVES_PER_BLOCK + wave;   // 0..8191
    const int idx  = sidx[s];

    // ---- issue class-logit loads (lanes 0..18) ----
    float oval = -INFINITY;
    int   ocls = 0x7fffffff;
    if (lane < FSE_K) {
        oval = outs[lane * FSE_HW + idx];
        ocls = lane;
    }

    // ---- issue the 8 scattered feature loads (independent, overlap latency) ----
    float f[8];
    #pragma unroll
    for (int j = 0; j < 8; ++j)
        f[j] = feats[(lane + 64 * j) * FSE_HW + idx];

    __syncthreads();   // protos staged

    // ---- argmax over 19 classes: max value, tie -> lowest index (matches jnp.argmax) ----
    #pragma unroll
    for (int off = 32; off; off >>= 1) {
        float v2 = __shfl_xor(oval, off);
        int   c2 = __shfl_xor(ocls, off);
        if (v2 > oval || (v2 == oval && c2 < ocls)) { oval = v2; ocls = c2; }
    }
    // all lanes now hold ocls

    // ---- per-lane fp64 partial sums: t_k = sum_c p*(p - 2f), f2 = sum_c f*f ----
    double t[FSE_K];
    #pragma unroll
    for (int k = 0; k < FSE_K; ++k) t[k] = 0.0;
    double f2 = 0.0;

    #pragma unroll
    for (int j = 0; j < 8; ++j) {
        const int c = lane + 64 * j;
        const double fd = (double)f[j];
        f2 = fma(fd, fd, f2);
        const double m2f = -2.0 * fd;   // exact
        #pragma unroll
        for (int k = 0; k < FSE_K; ++k) {
            const double p = (double)sP[k * FSE_C + c];   // bank = lane%32 -> conflict-free
            t[k] = fma(p, fma(1.0, p, m2f), t[k]);        // p*(p - 2f)
        }
    }

    // ---- butterfly reduce 20 doubles across the 64-lane wave ----
    #pragma unroll
    for (int off = 32; off; off >>= 1) {
        f2 += __shfl_xor(f2, off);
        #pragma unroll
        for (int k = 0; k < FSE_K; ++k) t[k] += __shfl_xor(t[k], off);
    }

    // ---- distances, clamp, rank of predicted class ----
    // d_k = f2 + t_k ; clip(d, 1e-12). No runtime register indexing (select chain).
    double dc = 0.0;
    #pragma unroll
    for (int k = 0; k < FSE_K; ++k) {
        double dk = f2 + t[k];
        dk = fmax(dk, 1e-12);
        if (k == ocls) dc = dk;
    }
    int rank = 0;
    #pragma unroll
    for (int k = 0; k < FSE_K; ++k) {
        double dk = f2 + t[k];
        dk = fmax(dk, 1e-12);
        // stable ascending argsort: earlier if smaller, or equal with lower index
        rank += (int)((dk < dc) || (dk == dc && k < ocls));
    }

    if (lane == 0)
        out[idx] = (float)rank * (1.0f / 18.0f);
}

extern "C" void kernel_launch(void* const* d_in, const int* in_sizes, int n_in,
                              void* d_out, int out_size, void* d_ws, size_t ws_size,
                              hipStream_t stream) {
    const float* feats  = (const float*)d_in[0];   // (1, 512, 512, 1024)
    const float* outs   = (const float*)d_in[1];   // (1, 19, 512, 1024)
    const float* protos = (const float*)d_in[2];   // (1, 19, 512)
    const int*   sidx   = (const int*)d_in[3];     // (8192,)
    float* out = (float*)d_out;                    // (512, 1024)

    // zero the full-resolution map (harness poisons d_out with 0xAA)
    fse_zero_kernel<<<FSE_HW / 4 / 256, 256, 0, stream>>>((float4*)out);

    // one wave per sample
    fse_main_kernel<<<FSE_NS / WAVES_PER_BLOCK, 256, 0, stream>>>(
        feats, outs, protos, sidx, out);
}

// Round 2
// 99.694 us; speedup vs baseline: 1.4069x; 1.4069x over previous
//
#include <hip/hip_runtime.h>
#include <hip/hip_bf16.h>
#include <math.h>

#define FSE_HW   524288   // 512 * 1024
#define FSE_C    512
#define FSE_K    19
#define FSE_NS   8192
#define FSE_GS   16                 // samples per block
#define FSE_NBLK (FSE_NS / FSE_GS)  // 512 blocks

// skewed prototype index: c*19 + k + (c>>5)  (keeps the 4 concurrent
// channel values, which differ by exactly 32, on distinct LDS banks)
__device__ __forceinline__ int pIdx(int c, int k) { return c * FSE_K + k + (c >> 5); }

__global__ __launch_bounds__(256) void fse_zero_kernel(float4* __restrict__ out) {
    int i = blockIdx.x * 256 + threadIdx.x;
    out[i] = make_float4(0.f, 0.f, 0.f, 0.f);
}

__global__ __launch_bounds__(256) void fse_main_kernel(
        const float* __restrict__ feats,    // (C, HW)
        const float* __restrict__ outs,     // (K, HW)
        const float* __restrict__ protos,   // (K, C)
        const int*   __restrict__ sidx,     // (NS,)
        float* __restrict__ out)            // (HW,)
{
    __shared__ float  sP[FSE_C * FSE_K + 16];      // transposed+skewed protos, ~39 KB
    __shared__ float  sLog[FSE_GS * FSE_K];        // gathered class logits
    __shared__ int    sIdx[FSE_GS];
    __shared__ double sRed[4][FSE_GS * 20];        // per-wave partials, 10 KB

    const int tid = threadIdx.x;
    const int g   = blockIdx.x;

    if (tid < FSE_GS) sIdx[tid] = sidx[g * FSE_GS + tid];

    // stage prototypes transposed (coalesced read, skewed LDS write)
    for (int i = tid; i < FSE_K * FSE_C; i += 256) {
        const int k = i / FSE_C, c = i % FSE_C;
        sP[pIdx(c, k)] = protos[i];
    }
    __syncthreads();

    // gather class logits for the block's 16 samples (19 lines each)
    for (int i = tid; i < FSE_GS * FSE_K; i += 256) {
        const int s = i / FSE_K, k = i % FSE_K;
        sLog[i] = outs[k * FSE_HW + sIdx[s]];
    }

    // ---- page-local feature gather + fp64 distance accumulation ----
    // lane = sample (4 bits) | channel-quarter (2 bits); wave owns 128 channels
    const int wave = tid >> 6, lane = tid & 63;
    const int s    = lane & 15;
    const int q    = lane >> 4;
    const int c0   = wave * 128 + q * 32;
    const float* A = feats + (size_t)c0 * FSE_HW + sIdx[s];

    double t[FSE_K];
    #pragma unroll
    for (int k = 0; k < FSE_K; ++k) t[k] = 0.0;
    double f2 = 0.0;

    #pragma unroll
    for (int j8 = 0; j8 < 4; ++j8) {           // 32 channels per lane, 8 at a time
        float f[8];
        #pragma unroll
        for (int u = 0; u < 8; ++u)
            f[u] = A[(size_t)(j8 * 8 + u) * FSE_HW];
        #pragma unroll
        for (int u = 0; u < 8; ++u) {
            const int c = c0 + j8 * 8 + u;
            const double fd  = (double)f[u];
            f2 = fma(fd, fd, f2);
            const double m2f = -2.0 * fd;       // exact
            #pragma unroll
            for (int k = 0; k < FSE_K; ++k) {
                const double p = (double)sP[pIdx(c, k)];   // 16-lane broadcast, 4 banks
                t[k] = fma(p, p + m2f, t[k]);              // p*(p-2f)
            }
        }
    }

    // reduce the 4 channel-quarters within the wave
    #pragma unroll
    for (int k = 0; k < FSE_K; ++k) {
        t[k] += __shfl_xor(t[k], 16);
        t[k] += __shfl_xor(t[k], 32);
    }
    f2 += __shfl_xor(f2, 16);
    f2 += __shfl_xor(f2, 32);

    if (lane < FSE_GS) {
        #pragma unroll
        for (int k = 0; k < FSE_K; ++k) sRed[wave][s * 20 + k] = t[k];
        sRed[wave][s * 20 + 19] = f2;
    }
    __syncthreads();

    // sum the 4 waves' partials (deterministic order)
    for (int cell = tid; cell < FSE_GS * 20; cell += 256)
        sRed[0][cell] = (sRed[0][cell] + sRed[1][cell]) + (sRed[2][cell] + sRed[3][cell]);
    __syncthreads();

    // ---- rank + scatter (one thread per sample) ----
    if (tid < FSE_GS) {
        const int ss = tid;
        float best = sLog[ss * FSE_K];
        int   ocls = 0;
        #pragma unroll
        for (int k = 1; k < FSE_K; ++k) {       // first-max, matches jnp.argmax
            const float v = sLog[ss * FSE_K + k];
            if (v > best) { best = v; ocls = k; }
        }
        const double f2s = sRed[0][ss * 20 + 19];
        double dc = 0.0;
        #pragma unroll
        for (int k = 0; k < FSE_K; ++k) {
            double dk = fmax(f2s + sRed[0][ss * 20 + k], 1e-12);
            if (k == ocls) dc = dk;
        }
        int rank = 0;
        #pragma unroll
        for (int k = 0; k < FSE_K; ++k) {
            double dk = fmax(f2s + sRed[0][ss * 20 + k], 1e-12);
            rank += (int)((dk < dc) || (dk == dc && k < ocls));
        }
        out[sIdx[ss]] = (float)rank * (1.0f / 18.0f);
    }
}

extern "C" void kernel_launch(void* const* d_in, const int* in_sizes, int n_in,
                              void* d_out, int out_size, void* d_ws, size_t ws_size,
                              hipStream_t stream) {
    const float* feats  = (const float*)d_in[0];
    const float* outs   = (const float*)d_in[1];
    const float* protos = (const float*)d_in[2];
    const int*   sidx   = (const int*)d_in[3];
    float* out = (float*)d_out;

    fse_zero_kernel<<<FSE_HW / 4 / 256, 256, 0, stream>>>((float4*)out);
    fse_main_kernel<<<FSE_NBLK, 256, 0, stream>>>(feats, outs, protos, sidx, out);
}